// Round 2
// baseline (16369.305 us; speedup 1.0000x reference)
//
#include <hip/hip_runtime.h>
#include <math.h>

#define B 256
#define H 512
#define T 256
#define V 28
#define G4 2048  // 4*H

#define OUT_MU 1835008          // T*B*V
#define OUT_LV (1835008+131072)

// fast transcendentals: inputs here are bounded (|g| ~ few units); clamp keeps
// __expf finite. error ~1e-6 relative, irrelevant vs f32 recurrence tolerance.
__device__ __forceinline__ float fast_sigmoid(float x) {
    x = fminf(fmaxf(x, -30.f), 30.f);
    return 1.0f / (1.0f + __expf(-x));
}
__device__ __forceinline__ float fast_tanh(float x) {
    x = fminf(fmaxf(x, -15.f), 15.f);
    float e = __expf(2.0f * x);
    return (e - 1.0f) / (e + 1.0f);
}

// ---------------------------------------------------------------------------
// K1: proj = embed @ Wi + b for enc (mat 0) and dec (mat 1).  [28,512]@[512,2048]
// grid 64 = 2 mats x 32 col-chunks(64), block 256.  Runs once, off critical path.
// ---------------------------------------------------------------------------
__global__ __launch_bounds__(256) void proj_kernel(
    const float* __restrict__ enc_embed, const float* __restrict__ enc_Wi, const float* __restrict__ enc_b,
    const float* __restrict__ dec_embed, const float* __restrict__ dec_Wi, const float* __restrict__ dec_b,
    float* __restrict__ enc_proj, float* __restrict__ dec_proj)
{
    __shared__ float emb[V][513];
    int mat = blockIdx.x >> 5;
    int cg  = blockIdx.x & 31;
    int c0  = cg * 64;
    const float* embed = mat ? dec_embed : enc_embed;
    const float* Wi    = mat ? dec_Wi    : enc_Wi;
    const float* bias  = mat ? dec_b     : enc_b;
    float*       proj  = mat ? dec_proj  : enc_proj;
    int tid = threadIdx.x;
    #pragma unroll
    for (int i = 0; i < 14; ++i) {
        int u = tid + i * 256;
        int r = u >> 7, q = u & 127;
        float4 vv = *(const float4*)&embed[r * H + q * 4];
        emb[r][q*4+0] = vv.x; emb[r][q*4+1] = vv.y; emb[r][q*4+2] = vv.z; emb[r][q*4+3] = vv.w;
    }
    __syncthreads();
    int col = c0 + (tid & 63);
    int rg  = tid >> 6;                  // 4 groups x 7 rows = 28
    float acc[7] = {0,0,0,0,0,0,0};
    for (int k = 0; k < H; ++k) {
        float w = Wi[k * G4 + col];
        #pragma unroll
        for (int r = 0; r < 7; ++r) acc[r] += w * emb[rg*7 + r][k];
    }
    float bb = bias[col];
    #pragma unroll
    for (int r = 0; r < 7; ++r) proj[(rg*7 + r) * G4 + col] = acc[r] + bb;
}

// ---------------------------------------------------------------------------
// K2: one LSTM step.
//   GEMM blocks (bid < nGemm): g = proj[tok] + h_in @ Wh -> gates -> h_out/c_out.
//     Tile: 64 batch-rows x 8 h-cols (32 g-cols), 256 threads, grid 256.
//   Fused logits (logit_t >= 0): each GEMM block also computes log_softmax of
//     h_in row `bid` (the hidden state the PREVIOUS launch produced) -> out.
//     Partials by all 256 threads up front (LDS lp[]), finished by lanes 0-31
//     of wave 0 while waves 2-3 run the gates epilogue.  No extra blocks =>
//     no serialized scheduling tail.
//   Standalone logit blocks (bid >= nGemm): used only by the final tail launch.
// ---------------------------------------------------------------------------
__global__ __launch_bounds__(256) void step_kernel(
    const float* __restrict__ proj,     // [V][2048], bias folded in
    const int*   __restrict__ tok_idx,  // per-row token, nullptr -> SOS(0)
    const float* __restrict__ Wh,       // [512][2048]
    const float* __restrict__ h_in,     // [256][512]
    const float* __restrict__ c_in,     // [256][512]
    float* __restrict__ h_out,
    float* __restrict__ c_out,
    const float* __restrict__ Wout,     // [512][28]
    const float* __restrict__ bout,     // [28]
    float* __restrict__ out,            // d_out base
    int nGemm, int logit_t)
{
    int tid = threadIdx.x;
    if ((int)blockIdx.x >= nGemm) {
        if (logit_t < 0) return;
        // ---- standalone logits: 8 rows per block, 1 row per half-wave ----
        int lb   = blockIdx.x - nGemm;
        int wid  = tid >> 6;
        int lane = tid & 63;
        int half = lane >> 5;
        int v    = lane & 31;
        int row  = lb * 8 + wid * 2 + half;
        float a0 = 0.f, a1 = 0.f, a2 = 0.f, a3 = 0.f;
        if (v < V) {
            const float* hr = h_in + row * H;
            #pragma unroll 4
            for (int k = 0; k < H; k += 4) {
                a0 += hr[k+0] * Wout[(k+0)*V + v];
                a1 += hr[k+1] * Wout[(k+1)*V + v];
                a2 += hr[k+2] * Wout[(k+2)*V + v];
                a3 += hr[k+3] * Wout[(k+3)*V + v];
            }
        }
        float val = (v < V) ? ((a0+a1) + (a2+a3) + bout[v]) : -INFINITY;
        float m = val;
        #pragma unroll
        for (int s = 16; s >= 1; s >>= 1) m = fmaxf(m, __shfl_xor(m, s, 32));
        float e = (v < V) ? __expf(val - m) : 0.f;
        #pragma unroll
        for (int s = 16; s >= 1; s >>= 1) e += __shfl_xor(e, s, 32);
        float lse = m + __logf(e);
        if (v < V) out[(logit_t * B + row) * V + v] = val - lse;
        return;
    }

    __shared__ float Ht[64][66];   // transposed h chunk [k][row]
    __shared__ float Ws[64][32];   // Wh chunk, 32 g-cols = 4 gates x 8
    __shared__ float Gs[64][36];   // g tile
    __shared__ float lp[256];      // fused-logit partials

    int bid = blockIdx.x;

    // ---- fused logit partials: row = bid, thread (v = tid&31, ks = tid>>5) ----
    if (logit_t >= 0) {
        int v = tid & 31, ks = tid >> 5;
        float lacc = 0.f;
        if (v < V) {
            const float* hr = h_in + bid * H + ks * 64;
            const float* wr = Wout + (ks * 64) * V + v;
            #pragma unroll 8
            for (int k = 0; k < 64; ++k) lacc += hr[k] * wr[k * V];
        }
        lp[tid] = lacc;
    }

    // ---- GEMM: 64 rows x 32 g-cols ----
    // XCD swizzle: round-robin dispatch (bid&7 = XCD) -> each XCD owns a
    // contiguous 8-wide cg band => its 512KB Wh slice stays L2-resident.
    int xcd = bid & 7, w = bid >> 3;
    int cg = xcd * 8 + (w & 7);    // 0..63 h-col group (8 cols)
    int rg = w >> 3;               // 0..3  row group (64 rows)
    int r0 = rg * 64, hc0 = cg * 8;
    int tx = tid & 7, ty = tid >> 3;       // tx: 4 g-cols, ty: 2 rows
    float acc0[4] = {0,0,0,0}, acc1[4] = {0,0,0,0};

    for (int k0 = 0; k0 < H; k0 += 64) {
        #pragma unroll
        for (int i = 0; i < 4; ++i) {      // h tile 64x64 (transposed scatter)
            int u = tid + i * 256;
            int rrow = u >> 4, kq = u & 15;
            float4 vv = *(const float4*)&h_in[(r0 + rrow) * H + k0 + kq * 4];
            Ht[kq*4+0][rrow] = vv.x; Ht[kq*4+1][rrow] = vv.y;
            Ht[kq*4+2][rrow] = vv.z; Ht[kq*4+3][rrow] = vv.w;
        }
        #pragma unroll
        for (int i = 0; i < 2; ++i) {      // Wh tile 64x32
            int u = tid + i * 256;
            int kk = u >> 3, f4 = u & 7;
            int gate = f4 >> 1, cc4 = (f4 & 1) * 4;
            float4 vv = *(const float4*)&Wh[(k0 + kk) * G4 + gate * 512 + hc0 + cc4];
            *(float4*)&Ws[kk][f4 * 4] = vv;
        }
        __syncthreads();
        #pragma unroll
        for (int kk = 0; kk < 64; ++kk) {
            float4 b4 = *(const float4*)&Ws[kk][tx * 4];
            float2 a2 = *(const float2*)&Ht[kk][ty * 2];
            acc0[0] += a2.x * b4.x; acc0[1] += a2.x * b4.y;
            acc0[2] += a2.x * b4.z; acc0[3] += a2.x * b4.w;
            acc1[0] += a2.y * b4.x; acc1[1] += a2.y * b4.y;
            acc1[2] += a2.y * b4.z; acc1[3] += a2.y * b4.w;
        }
        __syncthreads();
    }
    *(float4*)&Gs[ty*2+0][tx*4] = make_float4(acc0[0], acc0[1], acc0[2], acc0[3]);
    *(float4*)&Gs[ty*2+1][tx*4] = make_float4(acc1[0], acc1[1], acc1[2], acc1[3]);
    __syncthreads();

    if (tid >= 128) {
        // ---- gates epilogue: waves 2-3, float4, 4 outputs/thread ----
        int p   = tid - 128;               // 0..127
        int row = p >> 1, q = p & 1;
        int gr  = r0 + row;
        int j   = hc0 + q * 4;
        int tok = tok_idx ? tok_idx[gr] : 0;
        const float* pr = proj + tok * G4;
        float4 xi = *(const float4*)&Gs[row][     q*4];
        float4 xf = *(const float4*)&Gs[row][ 8 + q*4];
        float4 xg = *(const float4*)&Gs[row][16 + q*4];
        float4 xo = *(const float4*)&Gs[row][24 + q*4];
        float4 pi = *(const float4*)&pr[j];
        float4 pf = *(const float4*)&pr[512 + j];
        float4 pg = *(const float4*)&pr[1024 + j];
        float4 po = *(const float4*)&pr[1536 + j];
        float4 cv = *(const float4*)&c_in[gr * H + j];
        float4 cn, hn;
        cn.x = fast_sigmoid(xf.x+pf.x)*cv.x + fast_sigmoid(xi.x+pi.x)*fast_tanh(xg.x+pg.x);
        cn.y = fast_sigmoid(xf.y+pf.y)*cv.y + fast_sigmoid(xi.y+pi.y)*fast_tanh(xg.y+pg.y);
        cn.z = fast_sigmoid(xf.z+pf.z)*cv.z + fast_sigmoid(xi.z+pi.z)*fast_tanh(xg.z+pg.z);
        cn.w = fast_sigmoid(xf.w+pf.w)*cv.w + fast_sigmoid(xi.w+pi.w)*fast_tanh(xg.w+pg.w);
        hn.x = fast_sigmoid(xo.x+po.x)*fast_tanh(cn.x);
        hn.y = fast_sigmoid(xo.y+po.y)*fast_tanh(cn.y);
        hn.z = fast_sigmoid(xo.z+po.z)*fast_tanh(cn.z);
        hn.w = fast_sigmoid(xo.w+po.w)*fast_tanh(cn.w);
        *(float4*)&c_out[gr * H + j] = cn;
        *(float4*)&h_out[gr * H + j] = hn;
    } else if (tid < 32 && logit_t >= 0) {
        // ---- fused logit finish: lanes 0-31 of wave 0 ----
        int v = tid;
        float sum = 0.f;
        #pragma unroll
        for (int ks = 0; ks < 8; ++ks) sum += lp[ks * 32 + v];
        float val = (v < V) ? sum + bout[v] : -INFINITY;
        float m = val;
        #pragma unroll
        for (int s = 16; s >= 1; s >>= 1) m = fmaxf(m, __shfl_xor(m, s, 32));
        float e = (v < V) ? __expf(val - m) : 0.f;
        #pragma unroll
        for (int s = 16; s >= 1; s >>= 1) e += __shfl_xor(e, s, 32);
        float lse = m + __logf(e);
        if (v < V) out[(logit_t * B + bid) * V + v] = val - lse;
    }
}

// ---------------------------------------------------------------------------
// K3: mu = h@Wmu+bmu, logvar = h@Wlv+blv -> d_out.  grid 64
// ---------------------------------------------------------------------------
__global__ __launch_bounds__(256) void latent_kernel(
    const float* __restrict__ h,
    const float* __restrict__ Wmu, const float* __restrict__ bmu,
    const float* __restrict__ Wlv, const float* __restrict__ blv,
    float* __restrict__ dout)
{
    __shared__ float Ht[64][68];
    __shared__ float Ww[64][64];
    int bid = blockIdx.x;
    int mat = bid & 1;
    int cg  = (bid >> 1) & 7;
    int rg  = bid >> 4;
    int r0 = rg * 64, c0 = cg * 64;
    const float* W    = mat ? Wlv : Wmu;
    const float* bias = mat ? blv : bmu;
    float* outp = dout + (mat ? OUT_LV : OUT_MU);
    int tid = threadIdx.x;
    int tx = tid & 15, ty = tid >> 4;
    float acc[4][4] = {};
    for (int k0 = 0; k0 < H; k0 += 64) {
        #pragma unroll
        for (int i = 0; i < 4; ++i) {
            int u = tid + i * 256;
            int rrow = u >> 4, kq = u & 15;
            float4 vv = *(const float4*)&h[(r0 + rrow) * H + k0 + kq * 4];
            Ht[kq*4+0][rrow] = vv.x; Ht[kq*4+1][rrow] = vv.y;
            Ht[kq*4+2][rrow] = vv.z; Ht[kq*4+3][rrow] = vv.w;
        }
        #pragma unroll
        for (int i = 0; i < 4; ++i) {
            int u = tid + i * 256;
            int kk = u >> 4, f4 = u & 15;
            *(float4*)&Ww[kk][f4 * 4] = *(const float4*)&W[(k0 + kk) * H + c0 + f4 * 4];
        }
        __syncthreads();
        #pragma unroll
        for (int kk = 0; kk < 64; ++kk) {
            float4 a4 = *(const float4*)&Ht[kk][ty * 4];
            float4 b4 = *(const float4*)&Ww[kk][tx * 4];
            acc[0][0] += a4.x*b4.x; acc[0][1] += a4.x*b4.y; acc[0][2] += a4.x*b4.z; acc[0][3] += a4.x*b4.w;
            acc[1][0] += a4.y*b4.x; acc[1][1] += a4.y*b4.y; acc[1][2] += a4.y*b4.z; acc[1][3] += a4.y*b4.w;
            acc[2][0] += a4.z*b4.x; acc[2][1] += a4.z*b4.y; acc[2][2] += a4.z*b4.z; acc[2][3] += a4.z*b4.w;
            acc[3][0] += a4.w*b4.x; acc[3][1] += a4.w*b4.y; acc[3][2] += a4.w*b4.z; acc[3][3] += a4.w*b4.w;
        }
        __syncthreads();
    }
    #pragma unroll
    for (int i = 0; i < 4; ++i) {
        float4 st;
        st.x = acc[i][0] + bias[c0 + tx*4 + 0];
        st.y = acc[i][1] + bias[c0 + tx*4 + 1];
        st.z = acc[i][2] + bias[c0 + tx*4 + 2];
        st.w = acc[i][3] + bias[c0 + tx*4 + 3];
        *(float4*)&outp[(r0 + ty*4 + i) * H + c0 + tx*4] = st;
    }
}

// K3b: z = mu + eps * exp(0.5*logvar)
__global__ void z_kernel(const float* __restrict__ dout, const float* __restrict__ eps,
                         float* __restrict__ z)
{
    int i = blockIdx.x * 256 + threadIdx.x;
    float mu = dout[OUT_MU + i];
    float lv = dout[OUT_LV + i];
    z[i] = mu + eps[i] * __expf(0.5f * lv);
}

// ---------------------------------------------------------------------------
extern "C" void kernel_launch(void* const* d_in, const int* in_sizes, int n_in,
                              void* d_out, int out_size, void* d_ws, size_t ws_size,
                              hipStream_t stream)
{
    const int*   x         = (const int*)  d_in[0];
    const int*   target    = (const int*)  d_in[1];
    const float* hidden    = (const float*)d_in[2];
    const float* eps       = (const float*)d_in[3];
    const float* enc_embed = (const float*)d_in[4];
    const float* enc_Wi    = (const float*)d_in[5];
    const float* enc_Wh    = (const float*)d_in[6];
    const float* enc_b     = (const float*)d_in[7];
    const float* Wmu       = (const float*)d_in[8];
    const float* bmu       = (const float*)d_in[9];
    const float* Wlv       = (const float*)d_in[10];
    const float* blv       = (const float*)d_in[11];
    const float* dec_embed = (const float*)d_in[12];
    const float* dec_Wi    = (const float*)d_in[13];
    const float* dec_Wh    = (const float*)d_in[14];
    const float* dec_b     = (const float*)d_in[15];
    const float* Wout      = (const float*)d_in[16];
    const float* bout      = (const float*)d_in[17];
    float* out = (float*)d_out;
    float* ws  = (float*)d_ws;

    float* enc_proj = ws;                       // 28*2048
    float* dec_proj = enc_proj + V * G4;
    float* hA       = dec_proj + V * G4;        // 256*512
    float* hB       = hA + B * H;
    float* cb       = hB + B * H;
    float* zb       = cb + B * H;

    proj_kernel<<<64, 256, 0, stream>>>(enc_embed, enc_Wi, enc_b,
                                        dec_embed, dec_Wi, dec_b,
                                        enc_proj, dec_proj);
    // ---- encoder ----
    for (int t = 0; t < T; ++t) {
        const float* hi = (t == 0) ? hidden : ((t & 1) ? hB : hA);
        const float* ci = (t == 0) ? hidden : cb;
        float* ho = ((t + 1) & 1) ? hB : hA;
        step_kernel<<<256, 256, 0, stream>>>(enc_proj, x + t * B, enc_Wh,
                                             hi, ci, ho, cb,
                                             nullptr, nullptr, nullptr, 256, -1);
    }
    // final encoder h = hA
    latent_kernel<<<64, 256, 0, stream>>>(hA, Wmu, bmu, Wlv, blv, out);
    z_kernel<<<512, 256, 0, stream>>>(out, eps, zb);
    // ---- decoder: logits for step t's h fused into launch t+1 ----
    for (int t = 0; t < T; ++t) {
        const float* hi = (t == 0) ? zb : ((t & 1) ? hB : hA);
        const float* ci = (t == 0) ? zb : cb;
        float* ho = ((t + 1) & 1) ? hB : hA;
        const int* tok = (t == 0) ? nullptr : (target + (t - 1) * B);
        step_kernel<<<256, 256, 0, stream>>>(dec_proj, tok, dec_Wh,
                                             hi, ci, ho, cb,
                                             Wout, bout, out, 256, t - 1);
    }
    // logits for the last hidden state (hA after t=255)
    step_kernel<<<32, 256, 0, stream>>>(dec_proj, nullptr, dec_Wh,
                                        hA, nullptr, nullptr, nullptr,
                                        Wout, bout, out, 0, 255);
}